// Round 5
// baseline (221.447 us; speedup 1.0000x reference)
//
#include <hip/hip_runtime.h>
#include <math.h>

#define FRAME_LEN 400
#define NBINS 257
#define NMEL 80
#define MEL_FLOOR 1.192092955078125e-07f

constexpr int B = 16;
constexpr int T = 480000;
constexpr int F = 1 + (T - FRAME_LEN) / 160; // 2998

// ws float offsets
#define WS_TW256C 0      // 256
#define WS_TW256S 256
#define WS_TW64C  512    // 32
#define WS_TW64S  544
#define WS_UNP4C  576    // float4[64] = 256 floats (permuted W_512^{4*brev(l)+j})
#define WS_UNP4S  832
#define WS_K0     1088   // int[80]
#define WS_LEN    1168   // int[80]
#define WS_WGT    1280   // float[32*80]
#define WS_STAT   4096   // float[16][2][80]: mean, invstd

__device__ __forceinline__ int brev6(int x) { return (int)(__brev((unsigned)x) >> 26); }
__device__ __forceinline__ int specIdx(int k) { return k + ((k >> 5) << 2); } // injective, conflict-free skew

// ---------------- Kernel 0: build tables ----------------
__global__ __launch_bounds__(256) void setup_kernel(
    const float* __restrict__ fil, float* __restrict__ ws)
{
    const int t = threadIdx.x;
    float s, c;
    sincosf(-6.283185307179586f * (float)t / 256.0f, &s, &c);
    ws[WS_TW256C + t] = c; ws[WS_TW256S + t] = s;
    if (t < 32) {
        sincosf(-6.283185307179586f * (float)t / 64.0f, &s, &c);
        ws[WS_TW64C + t] = c; ws[WS_TW64S + t] = s;
    }
    if (t < 64) {
        int m = brev6(t);
        for (int j = 0; j < 4; ++j) {
            sincosf(-6.283185307179586f * (float)(4 * m + j) / 512.0f, &s, &c);
            ws[WS_UNP4C + 4 * t + j] = c;
            ws[WS_UNP4S + 4 * t + j] = s;
        }
    }
    // sparse mel compaction (parallel 3-way scan)
    __shared__ int sh_k0[3][NMEL], sh_k1[3][NMEL];
    __shared__ int sh_K0[NMEL], sh_LEN[NMEL];
    if (t < 240) {
        int m = t % NMEL, r = t / NMEL;
        int kb = r * 86, ke = (kb + 86 < NBINS) ? (kb + 86) : NBINS;
        int k0 = -1, k1 = -1;
        for (int k = kb; k < ke; ++k) {
            if (fil[k * NMEL + m] > 0.0f) { if (k0 < 0) k0 = k; k1 = k; }
        }
        sh_k0[r][m] = k0; sh_k1[r][m] = k1;
    }
    __syncthreads();
    if (t < NMEL) {
        int k0 = -1, k1 = -1;
        for (int r = 0; r < 3; ++r) {
            int a = sh_k0[r][t], b1 = sh_k1[r][t];
            if (a >= 0) { if (k0 < 0) k0 = a; k1 = b1; }
        }
        int len = (k0 < 0) ? 0 : (k1 - k0 + 1);
        if (len > 32) len = 32;
        if (k0 < 0) k0 = 0;
        ((int*)ws)[WS_K0 + t] = k0;
        ((int*)ws)[WS_LEN + t] = len;
        sh_K0[t] = k0; sh_LEN[t] = len;
    }
    __syncthreads();
    for (int idx = t; idx < 32 * NMEL; idx += 256) {
        int j = idx / NMEL, m = idx - j * NMEL;
        int k0 = sh_K0[m], len = sh_LEN[m];
        ws[WS_WGT + idx] = (j < len) ? fil[(k0 + j) * NMEL + m] : 0.0f;
    }
}

// ---------------- Kernel 1: wave-per-frame log-mel ----------------
__global__ __launch_bounds__(256) void frame_logmel_kernel(
    const float* __restrict__ wav,
    const float* __restrict__ win,
    const float* __restrict__ ws,
    float* __restrict__ mel_out)
{
    __shared__ float s_t256c[256], s_t256s[256];
    __shared__ float s_t64c[32], s_t64s[32];
    __shared__ float4 s_upc[64], s_ups[64];
    __shared__ float s_wgt[32 * NMEL];
    __shared__ int s_k0[NMEL], s_len[NMEL];
    __shared__ float2 s_win2[200];
    __shared__ float s_spec[4][296];

    const int t = threadIdx.x;
    s_t256c[t] = ws[WS_TW256C + t];
    s_t256s[t] = ws[WS_TW256S + t];
    if (t < 32) { s_t64c[t] = ws[WS_TW64C + t]; s_t64s[t] = ws[WS_TW64S + t]; }
    if (t < 64) {
        s_upc[t] = ((const float4*)(ws + WS_UNP4C))[t];
        s_ups[t] = ((const float4*)(ws + WS_UNP4S))[t];
    }
    for (int i = t; i < 32 * NMEL; i += 256) s_wgt[i] = ws[WS_WGT + i];
    if (t < NMEL) { s_k0[t] = ((const int*)ws)[WS_K0 + t]; s_len[t] = ((const int*)ws)[WS_LEN + t]; }
    if (t < 200) s_win2[t] = ((const float2*)win)[t];
    __syncthreads();  // the only barrier: tables ready

    const int l = t & 63, w = t >> 6;
    const int fr = blockIdx.x * 4 + w;
    const int b = fr / F, f = fr - b * F;
    const float2* src = (const float2*)(wav + (size_t)b * T + (size_t)f * 160);

    // load 4 sample-pairs per lane (complex pack z[p] = x[2p] + i x[2p+1]), p = 64j+l
    float xr[4], xi[4];
    float sum = 0.0f;
    #pragma unroll
    for (int j = 0; j < 4; ++j) {
        int p = 64 * j + l;
        float2 v = (p < 200) ? src[p] : make_float2(0.0f, 0.0f);
        xr[j] = v.x * 32768.0f;
        xi[j] = v.y * 32768.0f;
        sum += xr[j] + xi[j];
    }
    #pragma unroll
    for (int m = 32; m >= 1; m >>= 1) sum += __shfl_xor(sum, m);
    const float mean = sum * (1.0f / 400.0f);

    // preemphasis + window (natural order)
    float zr[4], zi[4];
    float carry = 0.0f;
    #pragma unroll
    for (int j = 0; j < 4; ++j) {
        float y = xi[j], x0 = xr[j];
        float up = __shfl(y, (l + 63) & 63);
        float nc = __shfl(y, 63);
        if (l == 0) up = (j == 0) ? x0 : carry;
        carry = nc;
        int p = 64 * j + l;
        float2 w2 = (p < 200) ? s_win2[p] : make_float2(0.0f, 0.0f);
        zr[j] = (x0 - 0.97f * up - 0.03f * mean) * w2.x;
        zi[j] = (y - 0.97f * x0 - 0.03f * mean) * w2.y;
    }

    // in-lane radix-4 first stage + W_256^{j*l} twiddles
    float Ar = zr[0] + zr[2], Ai = zi[0] + zi[2];
    float Br = zr[0] - zr[2], Bi = zi[0] - zi[2];
    float Cr = zr[1] + zr[3], Ci = zi[1] + zi[3];
    float Dr = zr[1] - zr[3], Di = zi[1] - zi[3];
    float u0r = Ar + Cr, u0i = Ai + Ci;
    float u1r = Br + Di, u1i = Bi - Dr;
    float u2r = Ar - Cr, u2i = Ai - Ci;
    float u3r = Br - Di, u3i = Bi + Dr;
    {
        float wr, wi, tr;
        wr = s_t256c[l];     wi = s_t256s[l];
        tr = u1r * wr - u1i * wi; u1i = u1r * wi + u1i * wr; u1r = tr;
        wr = s_t256c[2 * l]; wi = s_t256s[2 * l];
        tr = u2r * wr - u2i * wi; u2i = u2r * wi + u2i * wr; u2r = tr;
        wr = s_t256c[3 * l]; wi = s_t256s[3 * l];
        tr = u3r * wr - u3i * wi; u3i = u3r * wi + u3i * wr; u3r = tr;
    }

    // 4 independent 64-pt FFTs across lanes (radix-2 DIF, shfl_xor butterflies)
    #pragma unroll
    for (int h = 32; h >= 1; h >>= 1) {
        int idx = (l & (h - 1)) * (32 / h);
        bool hi = (l & h) != 0;
        float wr = hi ? s_t64c[idx] : 1.0f;
        float wi = hi ? s_t64s[idx] : 0.0f;
        float sg = hi ? -1.0f : 1.0f;
        #define BFLY(vr, vi)                                        \
        {                                                           \
            float pr = __shfl_xor(vr, h), pi = __shfl_xor(vi, h);   \
            float sr = fmaf(sg, vr, pr), si = fmaf(sg, vi, pi);     \
            vr = sr * wr - si * wi;                                 \
            vi = sr * wi + si * wr;                                 \
        }
        BFLY(u0r, u0i) BFLY(u1r, u1i) BFLY(u2r, u2i) BFLY(u3r, u3i)
        #undef BFLY
    }
    // lane l, reg j now holds Z[4*brev6(l) + j]

    // real-FFT unpack in-register; conj partner of (l,j) is (l^63, 4-j) for j=1..3
    const int m = brev6(l);
    float b1r = __shfl_xor(u3r, 63), b1i = __shfl_xor(u3i, 63);
    float b2r = __shfl_xor(u2r, 63), b2i = __shfl_xor(u2i, 63);
    float b3r = __shfl_xor(u1r, 63), b3i = __shfl_xor(u1i, 63);
    int l0 = brev6((64 - m) & 63);
    float b0r = __shfl(u0r, l0), b0i = __shfl(u0i, l0);
    float4 wc = s_upc[l], wn = s_ups[l];
    float sp[4];
    #define UNP(J, ar, ai, br, bi, twr, twi)                        \
    {                                                               \
        float Er = 0.5f * (ar + br), Ei = 0.5f * (ai - bi);         \
        float Or = 0.5f * (ai + bi), Oi = 0.5f * (br - ar);         \
        float Xr = Er + twr * Or - twi * Oi;                        \
        float Xi = Ei + twr * Oi + twi * Or;                        \
        sp[J] = Xr * Xr + Xi * Xi;                                  \
    }
    UNP(0, u0r, u0i, b0r, b0i, wc.x, wn.x)
    UNP(1, u1r, u1i, b1r, b1i, wc.y, wn.y)
    UNP(2, u2r, u2i, b2r, b2i, wc.z, wn.z)
    UNP(3, u3r, u3i, b3r, b3i, wc.w, wn.w)
    #undef UNP
    ((float4*)s_spec[w])[m + (m >> 3)] = make_float4(sp[0], sp[1], sp[2], sp[3]);
    if (l == 0) {
        float d = u0r - u0i;  // X[256] = Re(Z0) - Im(Z0)
        s_spec[w][specIdx(256)] = d * d;
    }

    // sparse mel projection (wave-private LDS; no barrier needed)
    const size_t outbase = (size_t)fr * NMEL;
    {
        int mel = l;
        int k0 = s_k0[mel], len = s_len[mel];
        float acc = 0.0f;
        for (int i = 0; i < len; ++i)
            acc = fmaf(s_spec[w][specIdx(k0 + i)], s_wgt[i * NMEL + mel], acc);
        mel_out[outbase + mel] = logf(fmaxf(acc, MEL_FLOOR));
    }
    if (l < 16) {
        int mel = 64 + l;
        int k0 = s_k0[mel], len = s_len[mel];
        float acc = 0.0f;
        for (int i = 0; i < len; ++i)
            acc = fmaf(s_spec[w][specIdx(k0 + i)], s_wgt[i * NMEL + mel], acc);
        mel_out[outbase + mel] = logf(fmaxf(acc, MEL_FLOOR));
    }
}

// ---------------- Kernel 2: per-(b, mel) stats ----------------
__global__ __launch_bounds__(640) void stats_kernel(
    const float* __restrict__ mel, float* __restrict__ ws)
{
    const int b = blockIdx.x;
    const int m = threadIdx.x;  // 0..79
    const int r = threadIdx.y;  // 0..7
    const float* base = mel + (size_t)b * F * NMEL + m;
    double s = 0.0, s2 = 0.0;
    for (int f = r; f < F; f += 8) {
        float v = base[(size_t)f * NMEL];
        s += (double)v;
        s2 += (double)v * (double)v;
    }
    __shared__ double shs[8][NMEL], shs2[8][NMEL];
    shs[r][m] = s; shs2[r][m] = s2;
    __syncthreads();
    if (r == 0) {
        for (int i = 1; i < 8; ++i) { s += shs[i][m]; s2 += shs2[i][m]; }
        double mean = s / (double)F;
        double var = (s2 - s * s / (double)F) / (double)(F - 1);
        ws[WS_STAT + b * 2 * NMEL + m] = (float)mean;
        ws[WS_STAT + b * 2 * NMEL + NMEL + m] = (float)(1.0 / sqrt(var + 1e-7));
    }
}

// ---------------- Kernel 3: normalize (float4) + mask ----------------
__global__ __launch_bounds__(256) void norm_mask_kernel(
    float* __restrict__ out, const float* __restrict__ ws)
{
    const float* stat = ws + WS_STAT;
    const int total4 = (B * F * NMEL) / 4;
    const int stride = gridDim.x * blockDim.x;
    float4* out4 = (float4*)out;
    for (int e4 = blockIdx.x * blockDim.x + threadIdx.x; e4 < total4; e4 += stride) {
        int e = e4 * 4;
        int b = e / (F * NMEL);
        int m = e % NMEL;
        const float* sb = stat + b * 2 * NMEL;
        float4 v = out4[e4];
        v.x = (v.x - sb[m + 0]) * sb[NMEL + m + 0];
        v.y = (v.y - sb[m + 1]) * sb[NMEL + m + 1];
        v.z = (v.z - sb[m + 2]) * sb[NMEL + m + 2];
        v.w = (v.w - sb[m + 3]) * sb[NMEL + m + 3];
        out4[e4] = v;
    }
    const int nmask = B * (F / 2);
    float* mask = out + (size_t)B * F * NMEL;
    for (int e = blockIdx.x * blockDim.x + threadIdx.x; e < nmask; e += stride)
        mask[e] = 1.0f;
}

extern "C" void kernel_launch(void* const* d_in, const int* in_sizes, int n_in,
                              void* d_out, int out_size, void* d_ws, size_t ws_size,
                              hipStream_t stream) {
    const float* wav = (const float*)d_in[0];
    const float* fil = (const float*)d_in[1];
    const float* win = (const float*)d_in[2];
    float* out = (float*)d_out;
    float* ws = (float*)d_ws;

    setup_kernel<<<1, 256, 0, stream>>>(fil, ws);
    frame_logmel_kernel<<<(B * F) / 4, 256, 0, stream>>>(wav, win, ws, out);  // 47968/4 = 11992
    stats_kernel<<<B, dim3(NMEL, 8), 0, stream>>>(out, ws);
    norm_mask_kernel<<<2048, 256, 0, stream>>>(out, ws);
}

// Round 6
// 132.221 us; speedup vs baseline: 1.6748x; 1.6748x over previous
//
#include <hip/hip_runtime.h>
#include <math.h>

#define FRAME_LEN 400
#define NBINS 257
#define NMEL 80
#define MEL_FLOOR 1.192092955078125e-07f

constexpr int B = 16;
constexpr int T = 480000;
constexpr int F = 1 + (T - FRAME_LEN) / 160; // 2998

// ws float offsets
#define WS_TW256C 0      // 256
#define WS_TW256S 256
#define WS_TW64C  512    // 32
#define WS_TW64S  544
#define WS_UNP4C  576    // float4[64] = 256 floats (permuted W_512^{4*brev(l)+j})
#define WS_UNP4S  832
#define WS_K0     1088   // int[80]
#define WS_LEN    1168   // int[80]
#define WS_WGT    1280   // float[32*80]
#define WS_PART   4096   // float[16][8][2][80] stats partials
#define WS_STAT   24576  // float[16][2][80]: mean, invstd

__device__ __forceinline__ int brev6(int x) { return (int)(__brev((unsigned)x) >> 26); }
__device__ __forceinline__ int specIdx(int k) { return k + ((k >> 5) << 2); } // injective, conflict-free skew

// ---------------- Kernel 0: build tables ----------------
__global__ __launch_bounds__(256) void setup_kernel(
    const float* __restrict__ fil, float* __restrict__ ws)
{
    const int t = threadIdx.x;
    float s, c;
    sincosf(-6.283185307179586f * (float)t / 256.0f, &s, &c);
    ws[WS_TW256C + t] = c; ws[WS_TW256S + t] = s;
    if (t < 32) {
        sincosf(-6.283185307179586f * (float)t / 64.0f, &s, &c);
        ws[WS_TW64C + t] = c; ws[WS_TW64S + t] = s;
    }
    if (t < 64) {
        int m = brev6(t);
        for (int j = 0; j < 4; ++j) {
            sincosf(-6.283185307179586f * (float)(4 * m + j) / 512.0f, &s, &c);
            ws[WS_UNP4C + 4 * t + j] = c;
            ws[WS_UNP4S + 4 * t + j] = s;
        }
    }
    // sparse mel compaction (parallel 3-way scan)
    __shared__ int sh_k0[3][NMEL], sh_k1[3][NMEL];
    __shared__ int sh_K0[NMEL], sh_LEN[NMEL];
    if (t < 240) {
        int m = t % NMEL, r = t / NMEL;
        int kb = r * 86, ke = (kb + 86 < NBINS) ? (kb + 86) : NBINS;
        int k0 = -1, k1 = -1;
        for (int k = kb; k < ke; ++k) {
            if (fil[k * NMEL + m] > 0.0f) { if (k0 < 0) k0 = k; k1 = k; }
        }
        sh_k0[r][m] = k0; sh_k1[r][m] = k1;
    }
    __syncthreads();
    if (t < NMEL) {
        int k0 = -1, k1 = -1;
        for (int r = 0; r < 3; ++r) {
            int a = sh_k0[r][t], b1 = sh_k1[r][t];
            if (a >= 0) { if (k0 < 0) k0 = a; k1 = b1; }
        }
        int len = (k0 < 0) ? 0 : (k1 - k0 + 1);
        if (len > 32) len = 32;
        if (k0 < 0) k0 = 0;
        ((int*)ws)[WS_K0 + t] = k0;
        ((int*)ws)[WS_LEN + t] = len;
        sh_K0[t] = k0; sh_LEN[t] = len;
    }
    __syncthreads();
    for (int idx = t; idx < 32 * NMEL; idx += 256) {
        int j = idx / NMEL, m = idx - j * NMEL;
        int k0 = sh_K0[m], len = sh_LEN[m];
        ws[WS_WGT + idx] = (j < len) ? fil[(k0 + j) * NMEL + m] : 0.0f;
    }
}

// ---------------- Kernel 1: wave-per-frame log-mel ----------------
__global__ __launch_bounds__(256) void frame_logmel_kernel(
    const float* __restrict__ wav,
    const float* __restrict__ win,
    const float* __restrict__ ws,
    float* __restrict__ mel_out)
{
    __shared__ float s_t256c[256], s_t256s[256];
    __shared__ float s_t64c[32], s_t64s[32];
    __shared__ float4 s_upc[64], s_ups[64];
    __shared__ float s_wgt[32 * NMEL];
    __shared__ int s_k0[NMEL], s_len[NMEL];
    __shared__ float2 s_win2[200];
    __shared__ float s_spec[4][296];

    const int t = threadIdx.x;
    s_t256c[t] = ws[WS_TW256C + t];
    s_t256s[t] = ws[WS_TW256S + t];
    if (t < 32) { s_t64c[t] = ws[WS_TW64C + t]; s_t64s[t] = ws[WS_TW64S + t]; }
    if (t < 64) {
        s_upc[t] = ((const float4*)(ws + WS_UNP4C))[t];
        s_ups[t] = ((const float4*)(ws + WS_UNP4S))[t];
    }
    for (int i = t; i < 32 * NMEL; i += 256) s_wgt[i] = ws[WS_WGT + i];
    if (t < NMEL) { s_k0[t] = ((const int*)ws)[WS_K0 + t]; s_len[t] = ((const int*)ws)[WS_LEN + t]; }
    if (t < 200) s_win2[t] = ((const float2*)win)[t];
    __syncthreads();  // the only barrier: tables ready

    const int l = t & 63, w = t >> 6;
    const int fr = blockIdx.x * 4 + w;
    const int b = fr / F, f = fr - b * F;
    const float2* src = (const float2*)(wav + (size_t)b * T + (size_t)f * 160);

    // load 4 sample-pairs per lane (complex pack z[p] = x[2p] + i x[2p+1]), p = 64j+l
    float xr[4], xi[4];
    float sum = 0.0f;
    #pragma unroll
    for (int j = 0; j < 4; ++j) {
        int p = 64 * j + l;
        float2 v = (p < 200) ? src[p] : make_float2(0.0f, 0.0f);
        xr[j] = v.x * 32768.0f;
        xi[j] = v.y * 32768.0f;
        sum += xr[j] + xi[j];
    }
    #pragma unroll
    for (int m = 32; m >= 1; m >>= 1) sum += __shfl_xor(sum, m);
    const float mean = sum * (1.0f / 400.0f);

    // preemphasis + window (natural order)
    float zr[4], zi[4];
    float carry = 0.0f;
    #pragma unroll
    for (int j = 0; j < 4; ++j) {
        float y = xi[j], x0 = xr[j];
        float up = __shfl(y, (l + 63) & 63);
        float nc = __shfl(y, 63);
        if (l == 0) up = (j == 0) ? x0 : carry;
        carry = nc;
        int p = 64 * j + l;
        float2 w2 = (p < 200) ? s_win2[p] : make_float2(0.0f, 0.0f);
        zr[j] = (x0 - 0.97f * up - 0.03f * mean) * w2.x;
        zi[j] = (y - 0.97f * x0 - 0.03f * mean) * w2.y;
    }

    // in-lane radix-4 first stage + W_256^{j*l} twiddles
    float Ar = zr[0] + zr[2], Ai = zi[0] + zi[2];
    float Br = zr[0] - zr[2], Bi = zi[0] - zi[2];
    float Cr = zr[1] + zr[3], Ci = zi[1] + zi[3];
    float Dr = zr[1] - zr[3], Di = zi[1] - zi[3];
    float u0r = Ar + Cr, u0i = Ai + Ci;
    float u1r = Br + Di, u1i = Bi - Dr;
    float u2r = Ar - Cr, u2i = Ai - Ci;
    float u3r = Br - Di, u3i = Bi + Dr;
    {
        float wr, wi, tr;
        wr = s_t256c[l];     wi = s_t256s[l];
        tr = u1r * wr - u1i * wi; u1i = u1r * wi + u1i * wr; u1r = tr;
        wr = s_t256c[2 * l]; wi = s_t256s[2 * l];
        tr = u2r * wr - u2i * wi; u2i = u2r * wi + u2i * wr; u2r = tr;
        wr = s_t256c[3 * l]; wi = s_t256s[3 * l];
        tr = u3r * wr - u3i * wi; u3i = u3r * wi + u3i * wr; u3r = tr;
    }

    // 4 independent 64-pt FFTs across lanes (radix-2 DIF, shfl_xor butterflies)
    #pragma unroll
    for (int h = 32; h >= 1; h >>= 1) {
        int idx = (l & (h - 1)) * (32 / h);
        bool hi = (l & h) != 0;
        float wr = hi ? s_t64c[idx] : 1.0f;
        float wi = hi ? s_t64s[idx] : 0.0f;
        float sg = hi ? -1.0f : 1.0f;
        #define BFLY(vr, vi)                                        \
        {                                                           \
            float pr = __shfl_xor(vr, h), pi = __shfl_xor(vi, h);   \
            float sr = fmaf(sg, vr, pr), si = fmaf(sg, vi, pi);     \
            vr = sr * wr - si * wi;                                 \
            vi = sr * wi + si * wr;                                 \
        }
        BFLY(u0r, u0i) BFLY(u1r, u1i) BFLY(u2r, u2i) BFLY(u3r, u3i)
        #undef BFLY
    }
    // lane l, reg j now holds Z[4*brev6(l) + j]

    // real-FFT unpack in-register; conj partner of (l,j) is (l^63, 4-j) for j=1..3
    const int m = brev6(l);
    float b1r = __shfl_xor(u3r, 63), b1i = __shfl_xor(u3i, 63);
    float b2r = __shfl_xor(u2r, 63), b2i = __shfl_xor(u2i, 63);
    float b3r = __shfl_xor(u1r, 63), b3i = __shfl_xor(u1i, 63);
    int l0 = brev6((64 - m) & 63);
    float b0r = __shfl(u0r, l0), b0i = __shfl(u0i, l0);
    float4 wc = s_upc[l], wn = s_ups[l];
    float sp[4];
    #define UNP(J, ar, ai, br, bi, twr, twi)                        \
    {                                                               \
        float Er = 0.5f * (ar + br), Ei = 0.5f * (ai - bi);         \
        float Or = 0.5f * (ai + bi), Oi = 0.5f * (br - ar);         \
        float Xr = Er + twr * Or - twi * Oi;                        \
        float Xi = Ei + twr * Oi + twi * Or;                        \
        sp[J] = Xr * Xr + Xi * Xi;                                  \
    }
    UNP(0, u0r, u0i, b0r, b0i, wc.x, wn.x)
    UNP(1, u1r, u1i, b1r, b1i, wc.y, wn.y)
    UNP(2, u2r, u2i, b2r, b2i, wc.z, wn.z)
    UNP(3, u3r, u3i, b3r, b3i, wc.w, wn.w)
    #undef UNP
    ((float4*)s_spec[w])[m + (m >> 3)] = make_float4(sp[0], sp[1], sp[2], sp[3]);
    if (l == 0) {
        float d = u0r - u0i;  // X[256] = Re(Z0) - Im(Z0)
        s_spec[w][specIdx(256)] = d * d;
    }

    // sparse mel projection (wave-private LDS; no barrier needed)
    const size_t outbase = (size_t)fr * NMEL;
    {
        int mel = l;
        int k0 = s_k0[mel], len = s_len[mel];
        float acc = 0.0f;
        for (int i = 0; i < len; ++i)
            acc = fmaf(s_spec[w][specIdx(k0 + i)], s_wgt[i * NMEL + mel], acc);
        mel_out[outbase + mel] = logf(fmaxf(acc, MEL_FLOOR));
    }
    if (l < 16) {
        int mel = 64 + l;
        int k0 = s_k0[mel], len = s_len[mel];
        float acc = 0.0f;
        for (int i = 0; i < len; ++i)
            acc = fmaf(s_spec[w][specIdx(k0 + i)], s_wgt[i * NMEL + mel], acc);
        mel_out[outbase + mel] = logf(fmaxf(acc, MEL_FLOOR));
    }
}

// ---------------- Kernel 2a: stats partials (128 blocks) ----------------
__global__ __launch_bounds__(640) void stats_partial_kernel(
    const float* __restrict__ mel, float* __restrict__ ws)
{
    const int b = blockIdx.x;
    const int c = blockIdx.y;        // chunk 0..7
    const int m = threadIdx.x;       // 0..79
    const int r = threadIdx.y;       // 0..7
    const int f0 = c * 375;
    const int f1 = (f0 + 375 < F) ? (f0 + 375) : F;

    const float* base = mel + ((size_t)b * F) * NMEL + m;
    float s = 0.0f, s2 = 0.0f;
    for (int f = f0 + r; f < f1; f += 8) {
        float v = base[(size_t)f * NMEL];
        s += v;
        s2 += v * v;
    }
    __shared__ float shs[8][NMEL], shs2[8][NMEL];
    shs[r][m] = s; shs2[r][m] = s2;
    __syncthreads();
    if (r == 0) {
        #pragma unroll
        for (int i = 1; i < 8; ++i) { s += shs[i][m]; s2 += shs2[i][m]; }
        float* part = ws + WS_PART;
        part[((b * 8 + c) * 2 + 0) * NMEL + m] = s;
        part[((b * 8 + c) * 2 + 1) * NMEL + m] = s2;
    }
}

// ---------------- Kernel 2b: finalize stats ----------------
__global__ __launch_bounds__(256) void stats_final_kernel(float* __restrict__ ws)
{
    const float* part = ws + WS_PART;
    float* stat = ws + WS_STAT;
    for (int i = threadIdx.x; i < B * NMEL; i += 256) {
        int b = i / NMEL, m = i - b * NMEL;
        double s = 0.0, s2 = 0.0;
        for (int c = 0; c < 8; ++c) {
            s += (double)part[((b * 8 + c) * 2 + 0) * NMEL + m];
            s2 += (double)part[((b * 8 + c) * 2 + 1) * NMEL + m];
        }
        double mean = s / (double)F;
        double var = (s2 - s * s / (double)F) / (double)(F - 1);
        stat[b * 2 * NMEL + m] = (float)mean;
        stat[b * 2 * NMEL + NMEL + m] = (float)(1.0 / sqrt(var + 1e-7));
    }
}

// ---------------- Kernel 3: normalize (float4) + mask ----------------
__global__ __launch_bounds__(256) void norm_mask_kernel(
    float* __restrict__ out, const float* __restrict__ ws)
{
    const float* stat = ws + WS_STAT;
    const int total4 = (B * F * NMEL) / 4;
    const int stride = gridDim.x * blockDim.x;
    float4* out4 = (float4*)out;
    for (int e4 = blockIdx.x * blockDim.x + threadIdx.x; e4 < total4; e4 += stride) {
        int e = e4 * 4;
        int b = e / (F * NMEL);
        int m = e % NMEL;
        const float* sb = stat + b * 2 * NMEL;
        float4 v = out4[e4];
        v.x = (v.x - sb[m + 0]) * sb[NMEL + m + 0];
        v.y = (v.y - sb[m + 1]) * sb[NMEL + m + 1];
        v.z = (v.z - sb[m + 2]) * sb[NMEL + m + 2];
        v.w = (v.w - sb[m + 3]) * sb[NMEL + m + 3];
        out4[e4] = v;
    }
    const int nmask = B * (F / 2);
    float* mask = out + (size_t)B * F * NMEL;
    for (int e = blockIdx.x * blockDim.x + threadIdx.x; e < nmask; e += stride)
        mask[e] = 1.0f;
}

extern "C" void kernel_launch(void* const* d_in, const int* in_sizes, int n_in,
                              void* d_out, int out_size, void* d_ws, size_t ws_size,
                              hipStream_t stream) {
    const float* wav = (const float*)d_in[0];
    const float* fil = (const float*)d_in[1];
    const float* win = (const float*)d_in[2];
    float* out = (float*)d_out;
    float* ws = (float*)d_ws;

    setup_kernel<<<1, 256, 0, stream>>>(fil, ws);
    frame_logmel_kernel<<<(B * F) / 4, 256, 0, stream>>>(wav, win, ws, out);  // 11992 blocks
    stats_partial_kernel<<<dim3(B, 8), dim3(NMEL, 8), 0, stream>>>(out, ws);
    stats_final_kernel<<<1, 256, 0, stream>>>(ws);
    norm_mask_kernel<<<2048, 256, 0, stream>>>(out, ws);
}